// Round 13
// baseline (904.661 us; speedup 1.0000x reference)
//
#include <hip/hip_runtime.h>
#include <stdint.h>

#define T_SEQ  1132
#define BATCH  128
#define HID    13
#define G4     52
#define NLAYER 100
#define NPIPE  8            // pipelines, 16 batch each
#define LPW    4            // compute waves (layers) per WG
#define NWGP   25           // WGs per pipeline
#define NTHR   384          // 6 waves: 0..3 compute, 4 DMA-in, 5 DMA-out
#define CH     4            // timesteps per chunk (1132 = 4*283)
#define NCH    283
#define RCL    4            // LDS staging slots (power of 2)
#define RC     8            // global ring chunk slots (power of 2)
#define NCLS   10
#define FEAT   (T_SEQ*HID)
#define L2E    1.44269504f  // log2(e)

#define CHUNK_U32 (CH*256)  // 1024 u32 per chunk (64 lanes x 16B x CH)
#define FLAG_BYTES 65536
#define RING_U32_PER_WG ((size_t)RC * CHUNK_U32)
#define RING_BYTES ((size_t)(NPIPE*NWGP) * RING_U32_PER_WG * 4)

typedef float  f32x4 __attribute__((ext_vector_type(4)));
typedef __fp16 f16x4 __attribute__((ext_vector_type(4)));
typedef unsigned int u32x4 __attribute__((ext_vector_type(4)));
typedef unsigned long long u64x2 __attribute__((ext_vector_type(2)));

struct HL { f16x4 h; f16x4 l; };   // 16B: hi-halves | lo-halves

// f16 hi/lo split: ~22 effective mantissa bits
__device__ __forceinline__ void f16split(float x, __fp16& hi, __fp16& lo) {
  hi = (__fp16)x;
  lo = (__fp16)(x - (float)hi);
}

__device__ __forceinline__ void lspin_ge(int* p, int need) {
  int v = __hip_atomic_load(p, __ATOMIC_ACQUIRE, __HIP_MEMORY_SCOPE_WORKGROUP);
  while (v < need) {
    __builtin_amdgcn_s_sleep(1);
    v = __hip_atomic_load(p, __ATOMIC_ACQUIRE, __HIP_MEMORY_SCOPE_WORKGROUP);
  }
}
__device__ __forceinline__ void gspin_ge(int* p, int need) {
  int v = __hip_atomic_load(p, __ATOMIC_RELAXED, __HIP_MEMORY_SCOPE_AGENT);
  while (v < need) {
    __builtin_amdgcn_s_sleep(1);
    v = __hip_atomic_load(p, __ATOMIC_RELAXED, __HIP_MEMORY_SCOPE_AGENT);
  }
}

// D[gate'][batch] orientation: A = weights (rows m~=lane&15 = gate-in-tile,
// k=quad*4+jj), B = Z (k=quad*4+jj, col=batch=lane&15). D: row=quad*4+reg,
// col=lane&15. Lane (quad,b) owns cells j~=4quad+r of batch b; the cell update
// writes next step's B-fragment IN REGISTERS (same lane) — no LDS round-trip
// on the h-recurrence. Handoff: one ds_write_b128 per lane/step.
//
// Gate prescaling: i/f/o weight+bias rows scaled by -log2(e), g rows by
// +2*log2(e); cell state carried as c_hat = 2*log2(e)*c. Merged-reciprocal
// sigmoid/tanh algebra (5 exp + 2 rcp per cell):
//   c_hat' = [c_hat*(1+A)(1+B) + 2L2E*(B-1)(1+C)] * rcp((1+A)(1+B)(1+C))
//   h      = (E-1) * rcp((1+D)(E+1)),  E = exp2(min(c_hat',100))
// where A=e^-i, B=e^{2g}, C=e^-f, D=e^-o.
//
// NOTE (measured, round 9): merging the hi/lo cross terms into one
// v_mfma_f32_16x16x32_f16 with slot-paired packing FAILED on hardware
// (absmax 6.3e-3 vs 2.2e-3) — gfx950's x32 A/B operand slot->k maps are not
// interchangeable. Keep the chained 3x 16x16x16 form (bit-exact, verified).
//
// Fine-grained relay: sProg/sProgOut count STEPS; producers release after
// each step's ds_write; consumers prefetch the NEXT GLOBAL step's
// {spin, ds_read, x-MFMA block} inside the current step's stall bubbles —
// rolling across chunk boundaries, so no per-chunk exposed prologue.
// sCons/sConsOut stay chunk-granular (slot backpressure unchanged).
__global__ __launch_bounds__(NTHR) void lstm_pipeline(
    const float* __restrict__ xin,   // [BATCH][T][HID]
    const float* __restrict__ w_ih,  // [L][G4][HID]
    const float* __restrict__ w_hh,  // [L][G4][HID]
    const float* __restrict__ b_ih,  // [L][G4]
    const float* __restrict__ b_hh,  // [L][G4]
    int*      flags,
    uint32_t* ring,
    float*    act)                   // [T][BATCH*HID]
{
  const int wg   = blockIdx.x;
  const int pp   = wg / NWGP;
  const int wgi  = wg - pp * NWGP;
  const int tid  = threadIdx.x;
  const int lane = tid & 63;
  const int nt   = tid >> 6;           // 0..3 compute, 4 DMA-in, 5 DMA-out
  const int quad = lane >> 4;
  const int b15  = lane & 15;          // batch column / A-row within tile
  const bool lastWG = (wgi == NWGP - 1);

  // staging: [layer][slot][step][256 u32] ; each lane owns u32[lane*4..+3] = HL
  __shared__ __align__(16) uint32_t sXP[LPW][RCL][CH][256];   // 64 KB
  __shared__ __align__(16) uint32_t sOutR[RCL][CH][256];      // 16 KB
  __shared__ int sProg[LPW];     // STEP-granular progress (steps staged)
  __shared__ int sCons[LPW];     // chunk-granular consumption
  __shared__ int sProgOut;       // STEP-granular
  __shared__ int sConsOut;       // chunk-granular

  int* flReadySelf = flags + ((pp * NWGP + wgi) * 2 + 0) * 16;
  int* flProgSelf  = flags + ((pp * NWGP + wgi) * 2 + 1) * 16;
  int* flReadyPrev = (wgi > 0) ? flags + ((pp * NWGP + wgi - 1) * 2 + 0) * 16 : flags;
  int* flProgNext  = (!lastWG) ? flags + ((pp * NWGP + wgi + 1) * 2 + 1) * 16 : flags;

  if (lane == 0) {
    if (nt == LPW + 1)  // DMA-out owns the "my chunks published" flag
      __hip_atomic_store(flReadySelf, 0, __ATOMIC_RELAXED, __HIP_MEMORY_SCOPE_AGENT);
    if (nt == LPW)      // DMA-in owns the "prev ring consumed" flag
      __hip_atomic_store(flProgSelf, 0, __ATOMIC_RELAXED, __HIP_MEMORY_SCOPE_AGENT);
  }
  if (tid < LPW) { sProg[tid] = 0; sCons[tid] = 0; }
  if (tid == 0) { sProgOut = 0; sConsOut = 0; }
  __syncthreads();   // the only barrier; waves free-run after this

  if (nt < LPW) {
    // ================= compute wave: layer l =================
    const int l = wgi * LPW + nt;
    const bool lastL = (l == NLAYER - 1);

    // Static A-fragments (f16 hi/lo): Wx and Wh, 4 gate-type tiles.
    // A[m~ = b15][k = quad*4+jj]; original gate row g = mt*13 + m~ (m~<13).
    f16x4 Axh[4], Axl[4], Ahh[4], Ahl[4];
    f32x4 biasv[4];
    #pragma unroll
    for (int mt = 0; mt < 4; ++mt) {
      const float gsc = (mt == 2) ? (2.0f * L2E) : (-L2E);
      #pragma unroll
      for (int jj = 0; jj < 4; ++jj) {
        int k = quad * 4 + jj;
        float wx = 0.f, wh = 0.f;
        if (b15 < HID && k < HID) {
          int g = mt * HID + b15;
          wx = w_ih[(size_t)(l * G4 + g) * HID + k];
          wh = w_hh[(size_t)(l * G4 + g) * HID + k];
        }
        wx *= gsc; wh *= gsc;
        __fp16 hi, lo;
        f16split(wx, hi, lo); Axh[mt][jj] = hi; Axl[mt][jj] = lo;
        f16split(wh, hi, lo); Ahh[mt][jj] = hi; Ahl[mt][jj] = lo;
      }
      #pragma unroll
      for (int r = 0; r < 4; ++r) {
        int jt = quad * 4 + r;   // cell row j~
        biasv[mt][r] = (jt < HID)
            ? gsc * (b_ih[l * G4 + mt * HID + jt] + b_hh[l * G4 + mt * HID + jt]) : 0.f;
      }
    }

    f16x4 Bhh = (f16x4)0, Bhl = (f16x4)0;   // h B-frag (own registers)
    float cst[4] = {0.f, 0.f, 0.f, 0.f};    // c_hat = 2*log2(e)*c

    // one-time x prologue: global step 0
    lspin_ge(&sProg[nt], 1);
    f32x4 axc[4];
    {
      u32x4 bx = *(const u32x4*)&sXP[nt][0][0][lane * 4];
      HL z = __builtin_bit_cast(HL, bx);
      #pragma unroll
      for (int mt = 0; mt < 4; ++mt) {
        f32x4 a = biasv[mt];
        a = __builtin_amdgcn_mfma_f32_16x16x16f16(Axh[mt], z.h, a, 0, 0, 0);
        a = __builtin_amdgcn_mfma_f32_16x16x16f16(Axl[mt], z.h, a, 0, 0, 0);
        a = __builtin_amdgcn_mfma_f32_16x16x16f16(Axh[mt], z.l, a, 0, 0, 0);
        axc[mt] = a;
      }
    }

    #pragma unroll 1
    for (int ci = 0; ci < NCH; ++ci) {
      const int slot = ci & (RCL - 1);
      const int base = ci * CH;

      if (ci + 1 - RCL > 0) {                       // output slot free
        if (nt < LPW - 1) lspin_ge(&sCons[nt + 1], ci + 1 - RCL);
        else              lspin_ge(&sConsOut,       ci + 1 - RCL);
      }

      // ---- CH steps; x-part for the NEXT global step is prefetched inside
      //      each step's MFMA-latency window (rolls across chunk boundary).
      #pragma unroll
      for (int s = 0; s < CH; ++s) {
        f32x4 acc[4];
        #pragma unroll
        for (int mt = 0; mt < 4; ++mt) {
          f32x4 a = axc[mt];
          a = __builtin_amdgcn_mfma_f32_16x16x16f16(Ahh[mt], Bhh, a, 0, 0, 0);
          a = __builtin_amdgcn_mfma_f32_16x16x16f16(Ahl[mt], Bhh, a, 0, 0, 0);
          a = __builtin_amdgcn_mfma_f32_16x16x16f16(Ahh[mt], Bhl, a, 0, 0, 0);
          acc[mt] = a;
        }

        // prefetch next global step's input + x-part (independent of acc/act)
        const int gnext = base + s + 1;
        if (gnext < T_SEQ) {
          lspin_ge(&sProg[nt], gnext + 1);
          const int slN = (gnext >> 2) & (RCL - 1);
          const int sN  = gnext & (CH - 1);
          u32x4 bx = *(const u32x4*)&sXP[nt][slN][sN][lane * 4];
          HL z = __builtin_bit_cast(HL, bx);
          #pragma unroll
          for (int mt = 0; mt < 4; ++mt) {
            f32x4 a = biasv[mt];
            a = __builtin_amdgcn_mfma_f32_16x16x16f16(Axh[mt], z.h, a, 0, 0, 0);
            a = __builtin_amdgcn_mfma_f32_16x16x16f16(Axl[mt], z.h, a, 0, 0, 0);
            a = __builtin_amdgcn_mfma_f32_16x16x16f16(Axh[mt], z.l, a, 0, 0, 0);
            axc[mt] = a;
          }
        }

        float hnv[4];
        #pragma unroll
        for (int r = 0; r < 4; ++r) {
          float eA = __builtin_amdgcn_exp2f(acc[0][r]);   // e^{-i}
          float eC = __builtin_amdgcn_exp2f(acc[1][r]);   // e^{-f}
          float eB = __builtin_amdgcn_exp2f(acc[2][r]);   // e^{2g}
          float eD = __builtin_amdgcn_exp2f(acc[3][r]);   // e^{-o}
          float ta = 1.0f + eA, tb = 1.0f + eB, tc = 1.0f + eC;
          float p  = ta * tb;
          float ri = __builtin_amdgcn_rcpf(p * tc);
          float num = fmaf((eB - 1.0f) * tc, 2.0f * L2E, cst[r] * p);
          float cn = num * ri;
          cst[r] = cn;
          float eE = __builtin_amdgcn_exp2f(fminf(cn, 100.0f));   // e^{2c}
          float r2 = __builtin_amdgcn_rcpf((eE + 1.0f) * (1.0f + eD));
          float h  = (eE - 1.0f) * r2;
          hnv[r] = h;
          __fp16 hi, lo; f16split(h, hi, lo);
          Bhh[r] = hi; Bhl[r] = lo;          // next step's B-frag, in place
        }
        // handoff (conflict-free b128) + per-step release
        if (nt < LPW - 1) {
          HL o; o.h = Bhh; o.l = Bhl;
          *(u32x4*)&sXP[nt + 1][slot][s][lane * 4] = __builtin_bit_cast(u32x4, o);
          if (lane == 0)
            __hip_atomic_store(&sProg[nt + 1], base + s + 1, __ATOMIC_RELEASE, __HIP_MEMORY_SCOPE_WORKGROUP);
        } else if (!lastL) {
          HL o; o.h = Bhh; o.l = Bhl;
          *(u32x4*)&sOutR[slot][s][lane * 4] = __builtin_bit_cast(u32x4, o);
          if (lane == 0)
            __hip_atomic_store(&sProgOut, base + s + 1, __ATOMIC_RELEASE, __HIP_MEMORY_SCOPE_WORKGROUP);
        } else {
          u32x4 w;
          #pragma unroll
          for (int r = 0; r < 4; ++r) w[r] = __float_as_uint(hnv[r]);
          *(u32x4*)&sOutR[slot][s][lane * 4] = w;
          if (lane == 0)
            __hip_atomic_store(&sProgOut, base + s + 1, __ATOMIC_RELEASE, __HIP_MEMORY_SCOPE_WORKGROUP);
        }
      }

      // input slot fully consumed (all reads completed -> release ordering)
      if (lane == 0)
        __hip_atomic_store(&sCons[nt], ci + 1, __ATOMIC_RELEASE, __HIP_MEMORY_SCOPE_WORKGROUP);
    }
  } else if (nt == LPW) {
    // ================= DMA-in wave (u64 ring atomics) =================
    const uint32_t* ringprev = ring + (size_t)(pp * NWGP + wgi - 1) * RING_U32_PER_WG;
    const size_t    xrow     = (size_t)(pp * 16 + b15) * (T_SEQ * HID);

    #pragma unroll 1
    for (int cin = 0; cin < NCH; ++cin) {
      const int slot = cin & (RCL - 1);
      if (cin + 1 - RCL > 0) lspin_ge(&sCons[0], cin + 1 - RCL);

      if (wgi > 0) {
        gspin_ge(flReadyPrev, cin + 1);
        const uint64_t* src = (const uint64_t*)(ringprev + (size_t)(cin & (RC - 1)) * CHUNK_U32);
        uint64_t v[CH][2];
        #pragma unroll
        for (int s = 0; s < CH; ++s)
          #pragma unroll
          for (int w = 0; w < 2; ++w)
            v[s][w] = __hip_atomic_load(&src[s * 128 + lane * 2 + w],
                                        __ATOMIC_RELAXED, __HIP_MEMORY_SCOPE_AGENT);
        #pragma unroll
        for (int s = 0; s < CH; ++s) {
          u64x2 t = { v[s][0], v[s][1] };
          *(u32x4*)&sXP[0][slot][s][lane * 4] = __builtin_bit_cast(u32x4, t);
        }
        asm volatile("s_waitcnt vmcnt(0)" ::: "memory");   // ring loads landed
        if (lane == 0)
          __hip_atomic_store(flProgSelf, cin + 1, __ATOMIC_RELAXED, __HIP_MEMORY_SCOPE_AGENT);
      } else {
        const int t0 = cin * CH;
        #pragma unroll
        for (int s = 0; s < CH; ++s) {
          HL o;
          #pragma unroll
          for (int jj = 0; jj < 4; ++jj) {
            int k = quad * 4 + jj;
            float v = (k < HID) ? xin[xrow + (size_t)(t0 + s) * HID + k] : 0.f;
            __fp16 hi, lo; f16split(v, hi, lo);
            o.h[jj] = hi; o.l[jj] = lo;
          }
          *(u32x4*)&sXP[0][slot][s][lane * 4] = __builtin_bit_cast(u32x4, o);
        }
      }
      if (lane == 0)   // step-granular units: whole chunk = CH steps
        __hip_atomic_store(&sProg[0], (cin + 1) * CH, __ATOMIC_RELEASE, __HIP_MEMORY_SCOPE_WORKGROUP);
    }
  } else {
    // ================= DMA-out wave (u64 ring atomics) =================
    uint32_t* ringmine = ring + (size_t)(pp * NWGP + wgi) * RING_U32_PER_WG;

    #pragma unroll 1
    for (int cout = 0; cout < NCH; ++cout) {
      const int slot = cout & (RCL - 1);
      lspin_ge(&sProgOut, (cout + 1) * CH);   // step-granular

      if (!lastWG) {
        if (cout + 1 - RC > 0) gspin_ge(flProgNext, cout + 1 - RC);
        uint64_t* dst = (uint64_t*)(ringmine + (size_t)(cout & (RC - 1)) * CHUNK_U32);
        #pragma unroll
        for (int s = 0; s < CH; ++s) {
          u32x4 v = *(const u32x4*)&sOutR[slot][s][lane * 4];
          u64x2 t = __builtin_bit_cast(u64x2, v);
          #pragma unroll
          for (int w = 0; w < 2; ++w)
            __hip_atomic_store(&dst[s * 128 + lane * 2 + w], t[w],
                               __ATOMIC_RELAXED, __HIP_MEMORY_SCOPE_AGENT);
        }
        asm volatile("s_waitcnt vmcnt(0)" ::: "memory");
        if (lane == 0) {
          __hip_atomic_store(flReadySelf, cout + 1, __ATOMIC_RELAXED, __HIP_MEMORY_SCOPE_AGENT);
          __hip_atomic_store(&sConsOut, cout + 1, __ATOMIC_RELEASE, __HIP_MEMORY_SCOPE_WORKGROUP);
        }
      } else {
        const int t0 = cout * CH;
        #pragma unroll
        for (int s = 0; s < CH; ++s) {
          u32x4 v = *(const u32x4*)&sOutR[slot][s][lane * 4];
          float* dst = act + (size_t)(t0 + s) * (BATCH * HID)
                     + (size_t)(pp * 16 + b15) * HID + quad * 4;
          #pragma unroll
          for (int r = 0; r < 4; ++r)
            if (quad * 4 + r < HID) dst[r] = __uint_as_float(v[r]);
        }
        if (lane == 0)
          __hip_atomic_store(&sConsOut, cout + 1, __ATOMIC_RELEASE, __HIP_MEMORY_SCOPE_WORKGROUP);
      }
    }
  }
}

__global__ __launch_bounds__(256) void linear_softmax(
    const float* __restrict__ act,    // [T][BATCH*HID]
    const float* __restrict__ w_lin,  // [NCLS][FEAT]
    const float* __restrict__ b_lin,
    float* __restrict__ out)          // [BATCH][NCLS]
{
  const int b   = blockIdx.x;
  const int tid = threadIdx.x;
  float accv[NCLS];
  #pragma unroll
  for (int c = 0; c < NCLS; ++c) accv[c] = 0.f;

  for (int i = tid; i < FEAT; i += 256) {
    int t = i / HID; int jj = i - t * HID;
    float a = act[(size_t)t * (BATCH * HID) + b * HID + jj];
    #pragma unroll
    for (int c = 0; c < NCLS; ++c)
      accv[c] += a * w_lin[(size_t)c * FEAT + i];
  }

  __shared__ float red[NCLS][256];
  #pragma unroll
  for (int c = 0; c < NCLS; ++c) red[c][tid] = accv[c];
  __syncthreads();
  for (int off = 128; off > 0; off >>= 1) {
    if (tid < off) {
      #pragma unroll
      for (int c = 0; c < NCLS; ++c) red[c][tid] += red[c][tid + off];
    }
    __syncthreads();
  }
  if (tid == 0) {
    float lg[NCLS]; float mx = -1e30f;
    #pragma unroll
    for (int c = 0; c < NCLS; ++c) { lg[c] = red[c][0] + b_lin[c]; mx = fmaxf(mx, lg[c]); }
    float sum = 0.f;
    #pragma unroll
    for (int c = 0; c < NCLS; ++c) { lg[c] = __expf(lg[c] - mx); sum += lg[c]; }
    float inv = 1.0f / sum;
    #pragma unroll
    for (int c = 0; c < NCLS; ++c) out[b * NCLS + c] = lg[c] * inv;
  }
}

extern "C" void kernel_launch(void* const* d_in, const int* in_sizes, int n_in,
                              void* d_out, int out_size, void* d_ws, size_t ws_size,
                              hipStream_t stream) {
  const float* xin  = (const float*)d_in[0];
  const float* wih  = (const float*)d_in[1];
  const float* whh  = (const float*)d_in[2];
  const float* bih  = (const float*)d_in[3];
  const float* bhh  = (const float*)d_in[4];
  const float* wlin = (const float*)d_in[5];
  const float* blin = (const float*)d_in[6];

  char*     ws    = (char*)d_ws;
  int*      flags = (int*)ws;
  uint32_t* ring  = (uint32_t*)(ws + FLAG_BYTES);
  float*    act   = (float*)(ws + FLAG_BYTES + RING_BYTES);

  lstm_pipeline<<<NPIPE * NWGP, NTHR, 0, stream>>>(xin, wih, whh, bih, bhh, flags, ring, act);
  linear_softmax<<<BATCH, 256, 0, stream>>>(act, wlin, blin, (float*)d_out);
}

// Round 15
// 862.422 us; speedup vs baseline: 1.0490x; 1.0490x over previous
//
#include <hip/hip_runtime.h>
#include <stdint.h>

#define T_SEQ  1132
#define BATCH  128
#define HID    13
#define G4     52
#define NLAYER 100
#define NPIPE  8            // pipelines, 16 batch each
#define LPW    4            // compute waves (layers) per WG
#define NWGP   25           // WGs per pipeline
#define NTHR   384          // 6 waves: 0..3 compute, 4 DMA-in, 5 DMA-out
#define CH     4            // timesteps per chunk (1132 = 4*283)
#define NCH    283
#define RCL    4            // LDS staging slots (power of 2)
#define RC     8            // global ring chunk slots (power of 2)
#define NCLS   10
#define FEAT   (T_SEQ*HID)
#define L2E    1.44269504f  // log2(e)

#define CHUNK_U32 (CH*256)  // 1024 u32 per chunk (64 lanes x 16B x CH)
#define FLAG_BYTES 65536
#define RING_U32_PER_WG ((size_t)RC * CHUNK_U32)
#define RING_BYTES ((size_t)(NPIPE*NWGP) * RING_U32_PER_WG * 4)

typedef float  f32x4 __attribute__((ext_vector_type(4)));
typedef __fp16 f16x4 __attribute__((ext_vector_type(4)));
typedef unsigned int u32x4 __attribute__((ext_vector_type(4)));
typedef unsigned long long u64x2 __attribute__((ext_vector_type(2)));

struct HL { f16x4 h; f16x4 l; };   // 16B: hi-halves | lo-halves

// f16 hi/lo split: ~22 effective mantissa bits
__device__ __forceinline__ void f16split(float x, __fp16& hi, __fp16& lo) {
  hi = (__fp16)x;
  lo = (__fp16)(x - (float)hi);
}

__device__ __forceinline__ void lspin_ge(int* p, int need) {
  int v = __hip_atomic_load(p, __ATOMIC_ACQUIRE, __HIP_MEMORY_SCOPE_WORKGROUP);
  while (v < need) {
    __builtin_amdgcn_s_sleep(1);
    v = __hip_atomic_load(p, __ATOMIC_ACQUIRE, __HIP_MEMORY_SCOPE_WORKGROUP);
  }
}
__device__ __forceinline__ void gspin_ge(int* p, int need) {
  int v = __hip_atomic_load(p, __ATOMIC_RELAXED, __HIP_MEMORY_SCOPE_AGENT);
  while (v < need) {
    __builtin_amdgcn_s_sleep(1);
    v = __hip_atomic_load(p, __ATOMIC_RELAXED, __HIP_MEMORY_SCOPE_AGENT);
  }
}

// D[gate'][batch] orientation: A = weights (rows m~=lane&15 = gate-in-tile,
// k=quad*4+jj), B = Z (k=quad*4+jj, col=batch=lane&15). D: row=quad*4+reg,
// col=lane&15. Lane (quad,b) owns cells j~=4quad+r of batch b; the cell update
// writes next step's B-fragment IN REGISTERS (same lane) — no LDS round-trip
// on the h-recurrence. Handoff: one ds_write_b128 per lane/step.
//
// Gate prescaling: i/f/o weight+bias rows scaled by -log2(e), g rows by
// +2*log2(e); cell state carried as c_hat = 2*log2(e)*c. Merged-reciprocal
// sigmoid/tanh algebra (5 exp + 2 rcp per cell):
//   c_hat' = [c_hat*(1+A)(1+B) + 2L2E*(B-1)(1+C)] * rcp((1+A)(1+B)(1+C))
//   h      = (E-1) * rcp((1+D)(E+1)),  E = exp2(min(c_hat',100))
// where A=e^-i, B=e^{2g}, C=e^-f, D=e^-o.
//
// NOTE (measured, round 9): merging the hi/lo cross terms into one
// v_mfma_f32_16x16x32_f16 with slot-paired packing FAILED on hardware
// (absmax 6.3e-3 vs 2.2e-3) — gfx950's x32 A/B operand slot->k maps are not
// interchangeable. Keep the chained 3x 16x16x16 form (bit-exact, verified).
//
// NOTE (measured, round 13): ROLLING the x-prefetch across the chunk
// boundary regressed 824->864 us: the boundary spin lands mid-step BEFORE
// the current step's handoff release, so when upstream is only ~2 steps
// ahead the stall propagates down all 100 layers. Keep the prefetch
// CHUNK-LOCAL (per-chunk prologue after the sCons wait) — never put an
// upstream-dependent wait between computing a result and releasing it.
//
// Fine-grained relay (measured 824 us w/ u32 DMA): sProg/sProgOut count
// STEPS; producers release after each step's ds_write; consumers prefetch
// step s+1's {spin, ds_read, x-MFMA} inside step s's stall bubbles.
// sCons/sConsOut stay chunk-granular (slot backpressure unchanged).
// Ring DMA uses u64 atomics (halves HBM write traffic: 880->445 MB, r13).
__global__ __launch_bounds__(NTHR) void lstm_pipeline(
    const float* __restrict__ xin,   // [BATCH][T][HID]
    const float* __restrict__ w_ih,  // [L][G4][HID]
    const float* __restrict__ w_hh,  // [L][G4][HID]
    const float* __restrict__ b_ih,  // [L][G4]
    const float* __restrict__ b_hh,  // [L][G4]
    int*      flags,
    uint32_t* ring,
    float*    act)                   // [T][BATCH*HID]
{
  const int wg   = blockIdx.x;
  const int pp   = wg / NWGP;
  const int wgi  = wg - pp * NWGP;
  const int tid  = threadIdx.x;
  const int lane = tid & 63;
  const int nt   = tid >> 6;           // 0..3 compute, 4 DMA-in, 5 DMA-out
  const int quad = lane >> 4;
  const int b15  = lane & 15;          // batch column / A-row within tile
  const bool lastWG = (wgi == NWGP - 1);

  // staging: [layer][slot][step][256 u32] ; each lane owns u32[lane*4..+3] = HL
  __shared__ __align__(16) uint32_t sXP[LPW][RCL][CH][256];   // 64 KB
  __shared__ __align__(16) uint32_t sOutR[RCL][CH][256];      // 16 KB
  __shared__ int sProg[LPW];     // STEP-granular progress (steps staged)
  __shared__ int sCons[LPW];     // chunk-granular consumption
  __shared__ int sProgOut;       // STEP-granular
  __shared__ int sConsOut;       // chunk-granular

  int* flReadySelf = flags + ((pp * NWGP + wgi) * 2 + 0) * 16;
  int* flProgSelf  = flags + ((pp * NWGP + wgi) * 2 + 1) * 16;
  int* flReadyPrev = (wgi > 0) ? flags + ((pp * NWGP + wgi - 1) * 2 + 0) * 16 : flags;
  int* flProgNext  = (!lastWG) ? flags + ((pp * NWGP + wgi + 1) * 2 + 1) * 16 : flags;

  if (lane == 0) {
    if (nt == LPW + 1)  // DMA-out owns the "my chunks published" flag
      __hip_atomic_store(flReadySelf, 0, __ATOMIC_RELAXED, __HIP_MEMORY_SCOPE_AGENT);
    if (nt == LPW)      // DMA-in owns the "prev ring consumed" flag
      __hip_atomic_store(flProgSelf, 0, __ATOMIC_RELAXED, __HIP_MEMORY_SCOPE_AGENT);
  }
  if (tid < LPW) { sProg[tid] = 0; sCons[tid] = 0; }
  if (tid == 0) { sProgOut = 0; sConsOut = 0; }
  __syncthreads();   // the only barrier; waves free-run after this

  if (nt < LPW) {
    // ================= compute wave: layer l =================
    const int l = wgi * LPW + nt;
    const bool lastL = (l == NLAYER - 1);

    // Static A-fragments (f16 hi/lo): Wx and Wh, 4 gate-type tiles.
    // A[m~ = b15][k = quad*4+jj]; original gate row g = mt*13 + m~ (m~<13).
    f16x4 Axh[4], Axl[4], Ahh[4], Ahl[4];
    f32x4 biasv[4];
    #pragma unroll
    for (int mt = 0; mt < 4; ++mt) {
      const float gsc = (mt == 2) ? (2.0f * L2E) : (-L2E);
      #pragma unroll
      for (int jj = 0; jj < 4; ++jj) {
        int k = quad * 4 + jj;
        float wx = 0.f, wh = 0.f;
        if (b15 < HID && k < HID) {
          int g = mt * HID + b15;
          wx = w_ih[(size_t)(l * G4 + g) * HID + k];
          wh = w_hh[(size_t)(l * G4 + g) * HID + k];
        }
        wx *= gsc; wh *= gsc;
        __fp16 hi, lo;
        f16split(wx, hi, lo); Axh[mt][jj] = hi; Axl[mt][jj] = lo;
        f16split(wh, hi, lo); Ahh[mt][jj] = hi; Ahl[mt][jj] = lo;
      }
      #pragma unroll
      for (int r = 0; r < 4; ++r) {
        int jt = quad * 4 + r;   // cell row j~
        biasv[mt][r] = (jt < HID)
            ? gsc * (b_ih[l * G4 + mt * HID + jt] + b_hh[l * G4 + mt * HID + jt]) : 0.f;
      }
    }

    f16x4 Bhh = (f16x4)0, Bhl = (f16x4)0;   // h B-frag (own registers)
    float cst[4] = {0.f, 0.f, 0.f, 0.f};    // c_hat = 2*log2(e)*c

    #pragma unroll 1
    for (int ci = 0; ci < NCH; ++ci) {
      const int slot = ci & (RCL - 1);
      const int base = ci * CH;

      if (ci + 1 - RCL > 0) {                       // output slot free
        if (nt < LPW - 1) lspin_ge(&sCons[nt + 1], ci + 1 - RCL);
        else              lspin_ge(&sConsOut,       ci + 1 - RCL);
      }

      // prologue: step 0's input + its x-part (bias + 3 x-MFMAs chained)
      lspin_ge(&sProg[nt], base + 1);
      f32x4 axc[4];
      {
        u32x4 bx = *(const u32x4*)&sXP[nt][slot][0][lane * 4];
        HL z = __builtin_bit_cast(HL, bx);
        #pragma unroll
        for (int mt = 0; mt < 4; ++mt) {
          f32x4 a = biasv[mt];
          a = __builtin_amdgcn_mfma_f32_16x16x16f16(Axh[mt], z.h, a, 0, 0, 0);
          a = __builtin_amdgcn_mfma_f32_16x16x16f16(Axl[mt], z.h, a, 0, 0, 0);
          a = __builtin_amdgcn_mfma_f32_16x16x16f16(Axh[mt], z.l, a, 0, 0, 0);
          axc[mt] = a;
        }
      }

      // ---- CH steps, software-pipelined: h-MFMAs(s) issue, then prefetch
      //      {spin, read, x-MFMAs}(s+1) fills the acc-latency window, then
      //      activation(s). Chunk-local only (see round-13 note).
      #pragma unroll
      for (int s = 0; s < CH; ++s) {
        f32x4 acc[4];
        #pragma unroll
        for (int mt = 0; mt < 4; ++mt) {
          f32x4 a = axc[mt];
          a = __builtin_amdgcn_mfma_f32_16x16x16f16(Ahh[mt], Bhh, a, 0, 0, 0);
          a = __builtin_amdgcn_mfma_f32_16x16x16f16(Ahl[mt], Bhh, a, 0, 0, 0);
          a = __builtin_amdgcn_mfma_f32_16x16x16f16(Ahh[mt], Bhl, a, 0, 0, 0);
          acc[mt] = a;
        }

        // prefetch next step's input + x-part (independent of acc/act)
        if (s < CH - 1) {
          lspin_ge(&sProg[nt], base + s + 2);
          u32x4 bx = *(const u32x4*)&sXP[nt][slot][s + 1][lane * 4];
          HL z = __builtin_bit_cast(HL, bx);
          #pragma unroll
          for (int mt = 0; mt < 4; ++mt) {
            f32x4 a = biasv[mt];
            a = __builtin_amdgcn_mfma_f32_16x16x16f16(Axh[mt], z.h, a, 0, 0, 0);
            a = __builtin_amdgcn_mfma_f32_16x16x16f16(Axl[mt], z.h, a, 0, 0, 0);
            a = __builtin_amdgcn_mfma_f32_16x16x16f16(Axh[mt], z.l, a, 0, 0, 0);
            axc[mt] = a;
          }
        }

        float hnv[4];
        #pragma unroll
        for (int r = 0; r < 4; ++r) {
          float eA = __builtin_amdgcn_exp2f(acc[0][r]);   // e^{-i}
          float eC = __builtin_amdgcn_exp2f(acc[1][r]);   // e^{-f}
          float eB = __builtin_amdgcn_exp2f(acc[2][r]);   // e^{2g}
          float eD = __builtin_amdgcn_exp2f(acc[3][r]);   // e^{-o}
          float ta = 1.0f + eA, tb = 1.0f + eB, tc = 1.0f + eC;
          float p  = ta * tb;
          float ri = __builtin_amdgcn_rcpf(p * tc);
          float num = fmaf((eB - 1.0f) * tc, 2.0f * L2E, cst[r] * p);
          float cn = num * ri;
          cst[r] = cn;
          float eE = __builtin_amdgcn_exp2f(fminf(cn, 100.0f));   // e^{2c}
          float r2 = __builtin_amdgcn_rcpf((eE + 1.0f) * (1.0f + eD));
          float h  = (eE - 1.0f) * r2;
          hnv[r] = h;
          __fp16 hi, lo; f16split(h, hi, lo);
          Bhh[r] = hi; Bhl[r] = lo;          // next step's B-frag, in place
        }
        // handoff (conflict-free b128) + per-step release
        if (nt < LPW - 1) {
          HL o; o.h = Bhh; o.l = Bhl;
          *(u32x4*)&sXP[nt + 1][slot][s][lane * 4] = __builtin_bit_cast(u32x4, o);
          if (lane == 0)
            __hip_atomic_store(&sProg[nt + 1], base + s + 1, __ATOMIC_RELEASE, __HIP_MEMORY_SCOPE_WORKGROUP);
        } else if (!lastL) {
          HL o; o.h = Bhh; o.l = Bhl;
          *(u32x4*)&sOutR[slot][s][lane * 4] = __builtin_bit_cast(u32x4, o);
          if (lane == 0)
            __hip_atomic_store(&sProgOut, base + s + 1, __ATOMIC_RELEASE, __HIP_MEMORY_SCOPE_WORKGROUP);
        } else {
          u32x4 w;
          #pragma unroll
          for (int r = 0; r < 4; ++r) w[r] = __float_as_uint(hnv[r]);
          *(u32x4*)&sOutR[slot][s][lane * 4] = w;
          if (lane == 0)
            __hip_atomic_store(&sProgOut, base + s + 1, __ATOMIC_RELEASE, __HIP_MEMORY_SCOPE_WORKGROUP);
        }
      }

      // input slot fully consumed (all reads completed -> release ordering)
      if (lane == 0)
        __hip_atomic_store(&sCons[nt], ci + 1, __ATOMIC_RELEASE, __HIP_MEMORY_SCOPE_WORKGROUP);
    }
  } else if (nt == LPW) {
    // ================= DMA-in wave (u64 ring atomics) =================
    const uint32_t* ringprev = ring + (size_t)(pp * NWGP + wgi - 1) * RING_U32_PER_WG;
    const size_t    xrow     = (size_t)(pp * 16 + b15) * (T_SEQ * HID);

    #pragma unroll 1
    for (int cin = 0; cin < NCH; ++cin) {
      const int slot = cin & (RCL - 1);
      if (cin + 1 - RCL > 0) lspin_ge(&sCons[0], cin + 1 - RCL);

      if (wgi > 0) {
        gspin_ge(flReadyPrev, cin + 1);
        const uint64_t* src = (const uint64_t*)(ringprev + (size_t)(cin & (RC - 1)) * CHUNK_U32);
        uint64_t v[CH][2];
        #pragma unroll
        for (int s = 0; s < CH; ++s)
          #pragma unroll
          for (int w = 0; w < 2; ++w)
            v[s][w] = __hip_atomic_load(&src[s * 128 + lane * 2 + w],
                                        __ATOMIC_RELAXED, __HIP_MEMORY_SCOPE_AGENT);
        #pragma unroll
        for (int s = 0; s < CH; ++s) {
          u64x2 t = { v[s][0], v[s][1] };
          *(u32x4*)&sXP[0][slot][s][lane * 4] = __builtin_bit_cast(u32x4, t);
        }
        asm volatile("s_waitcnt vmcnt(0)" ::: "memory");   // ring loads landed
        if (lane == 0)
          __hip_atomic_store(flProgSelf, cin + 1, __ATOMIC_RELAXED, __HIP_MEMORY_SCOPE_AGENT);
      } else {
        const int t0 = cin * CH;
        #pragma unroll
        for (int s = 0; s < CH; ++s) {
          HL o;
          #pragma unroll
          for (int jj = 0; jj < 4; ++jj) {
            int k = quad * 4 + jj;
            float v = (k < HID) ? xin[xrow + (size_t)(t0 + s) * HID + k] : 0.f;
            __fp16 hi, lo; f16split(v, hi, lo);
            o.h[jj] = hi; o.l[jj] = lo;
          }
          *(u32x4*)&sXP[0][slot][s][lane * 4] = __builtin_bit_cast(u32x4, o);
        }
      }
      if (lane == 0)   // step-granular units: whole chunk = CH steps
        __hip_atomic_store(&sProg[0], (cin + 1) * CH, __ATOMIC_RELEASE, __HIP_MEMORY_SCOPE_WORKGROUP);
    }
  } else {
    // ================= DMA-out wave (u64 ring atomics) =================
    uint32_t* ringmine = ring + (size_t)(pp * NWGP + wgi) * RING_U32_PER_WG;

    #pragma unroll 1
    for (int cout = 0; cout < NCH; ++cout) {
      const int slot = cout & (RCL - 1);
      lspin_ge(&sProgOut, (cout + 1) * CH);   // step-granular

      if (!lastWG) {
        if (cout + 1 - RC > 0) gspin_ge(flProgNext, cout + 1 - RC);
        uint64_t* dst = (uint64_t*)(ringmine + (size_t)(cout & (RC - 1)) * CHUNK_U32);
        #pragma unroll
        for (int s = 0; s < CH; ++s) {
          u32x4 v = *(const u32x4*)&sOutR[slot][s][lane * 4];
          u64x2 t = __builtin_bit_cast(u64x2, v);
          #pragma unroll
          for (int w = 0; w < 2; ++w)
            __hip_atomic_store(&dst[s * 128 + lane * 2 + w], t[w],
                               __ATOMIC_RELAXED, __HIP_MEMORY_SCOPE_AGENT);
        }
        asm volatile("s_waitcnt vmcnt(0)" ::: "memory");
        if (lane == 0) {
          __hip_atomic_store(flReadySelf, cout + 1, __ATOMIC_RELAXED, __HIP_MEMORY_SCOPE_AGENT);
          __hip_atomic_store(&sConsOut, cout + 1, __ATOMIC_RELEASE, __HIP_MEMORY_SCOPE_WORKGROUP);
        }
      } else {
        const int t0 = cout * CH;
        #pragma unroll
        for (int s = 0; s < CH; ++s) {
          u32x4 v = *(const u32x4*)&sOutR[slot][s][lane * 4];
          float* dst = act + (size_t)(t0 + s) * (BATCH * HID)
                     + (size_t)(pp * 16 + b15) * HID + quad * 4;
          #pragma unroll
          for (int r = 0; r < 4; ++r)
            if (quad * 4 + r < HID) dst[r] = __uint_as_float(v[r]);
        }
        if (lane == 0)
          __hip_atomic_store(&sConsOut, cout + 1, __ATOMIC_RELEASE, __HIP_MEMORY_SCOPE_WORKGROUP);
      }
    }
  }
}

__global__ __launch_bounds__(256) void linear_softmax(
    const float* __restrict__ act,    // [T][BATCH*HID]
    const float* __restrict__ w_lin,  // [NCLS][FEAT]
    const float* __restrict__ b_lin,
    float* __restrict__ out)          // [BATCH][NCLS]
{
  const int b   = blockIdx.x;
  const int tid = threadIdx.x;
  float accv[NCLS];
  #pragma unroll
  for (int c = 0; c < NCLS; ++c) accv[c] = 0.f;

  for (int i = tid; i < FEAT; i += 256) {
    int t = i / HID; int jj = i - t * HID;
    float a = act[(size_t)t * (BATCH * HID) + b * HID + jj];
    #pragma unroll
    for (int c = 0; c < NCLS; ++c)
      accv[c] += a * w_lin[(size_t)c * FEAT + i];
  }

  __shared__ float red[NCLS][256];
  #pragma unroll
  for (int c = 0; c < NCLS; ++c) red[c][tid] = accv[c];
  __syncthreads();
  for (int off = 128; off > 0; off >>= 1) {
    if (tid < off) {
      #pragma unroll
      for (int c = 0; c < NCLS; ++c) red[c][tid] += red[c][tid + off];
    }
    __syncthreads();
  }
  if (tid == 0) {
    float lg[NCLS]; float mx = -1e30f;
    #pragma unroll
    for (int c = 0; c < NCLS; ++c) { lg[c] = red[c][0] + b_lin[c]; mx = fmaxf(mx, lg[c]); }
    float sum = 0.f;
    #pragma unroll
    for (int c = 0; c < NCLS; ++c) { lg[c] = __expf(lg[c] - mx); sum += lg[c]; }
    float inv = 1.0f / sum;
    #pragma unroll
    for (int c = 0; c < NCLS; ++c) out[b * NCLS + c] = lg[c] * inv;
  }
}

extern "C" void kernel_launch(void* const* d_in, const int* in_sizes, int n_in,
                              void* d_out, int out_size, void* d_ws, size_t ws_size,
                              hipStream_t stream) {
  const float* xin  = (const float*)d_in[0];
  const float* wih  = (const float*)d_in[1];
  const float* whh  = (const float*)d_in[2];
  const float* bih  = (const float*)d_in[3];
  const float* bhh  = (const float*)d_in[4];
  const float* wlin = (const float*)d_in[5];
  const float* blin = (const float*)d_in[6];

  char*     ws    = (char*)d_ws;
  int*      flags = (int*)ws;
  uint32_t* ring  = (uint32_t*)(ws + FLAG_BYTES);
  float*    act   = (float*)(ws + FLAG_BYTES + RING_BYTES);

  lstm_pipeline<<<NPIPE * NWGP, NTHR, 0, stream>>>(xin, wih, whh, bih, bhh, flags, ring, act);
  linear_softmax<<<BATCH, 256, 0, stream>>>(act, wlin, blin, (float*)d_out);
}